// Round 9
// baseline (130.416 us; speedup 1.0000x reference)
//
#include <hip/hip_runtime.h>
#include <hip/hip_bf16.h>

#define NN 8192
#define FIN 256
#define FOUT 128
#define FP 144              // 128 h-cols + denom col (128) + 15 zero pad
#define KSPLIT 8
#define KCH (NN / KSPLIT)   // 1024
#define NT (KCH / 32)       // 32 k-steps of 32
#define NP (KCH / 128)      // 8 panels of 128k
#define PANEL_BYTES (FP * 256)  // 36864

typedef __attribute__((ext_vector_type(8))) short short8;
typedef __attribute__((ext_vector_type(4))) float f32x4;
typedef __attribute__((ext_vector_type(4))) int i32x4;
typedef __attribute__((ext_vector_type(4))) unsigned int u32x4;
typedef unsigned short u16;
typedef unsigned int u32;

__device__ inline u16 bf16r(float v) {
  return __builtin_bit_cast(u16, __float2bfloat16(v));
}

// ---- fused: h = x@W (regs), e = leaky_relu(h@a), w = exp(e),
//      gT[f][j] = bf16(w_j*h_jf) f<128; gT[128][j] = bf16(w_j); 129..143 = 0 ----
__global__ __launch_bounds__(256) void k_prep(const float* __restrict__ x,
                                              const float* __restrict__ W,
                                              const float* __restrict__ a,
                                              u16* __restrict__ gT) {
  __shared__ float xs[32 * 256];
  __shared__ float ap[4][16];
  __shared__ float wsh[32];
  __shared__ u16 gsh[32][132];
  const int t = threadIdx.x;
  const int r0 = blockIdx.x * 32;

  const float4* xg = (const float4*)(x + (size_t)r0 * FIN);
  float4* xs4 = (float4*)xs;
#pragma unroll
  for (int p = 0; p < 8; ++p) xs4[p * 256 + t] = xg[p * 256 + t];
  __syncthreads();

  const int f = t & 127;
  const int half = t >> 7;
  float acc[16];
#pragma unroll
  for (int i = 0; i < 16; ++i) acc[i] = 0.f;

  const float4* xsr = (const float4*)(xs + half * 16 * 256);
  for (int k4 = 0; k4 < 64; ++k4) {
    float w0 = W[(k4 * 4 + 0) * FOUT + f];
    float w1 = W[(k4 * 4 + 1) * FOUT + f];
    float w2 = W[(k4 * 4 + 2) * FOUT + f];
    float w3 = W[(k4 * 4 + 3) * FOUT + f];
#pragma unroll
    for (int i = 0; i < 16; ++i) {
      float4 xv = xsr[i * 64 + k4];
      acc[i] = fmaf(xv.x, w0, acc[i]);
      acc[i] = fmaf(xv.y, w1, acc[i]);
      acc[i] = fmaf(xv.z, w2, acc[i]);
      acc[i] = fmaf(xv.w, w3, acc[i]);
    }
  }

  const float af = a[f];
  float part[16];
#pragma unroll
  for (int i = 0; i < 16; ++i) part[i] = acc[i] * af;
#pragma unroll
  for (int i = 0; i < 16; ++i) {
#pragma unroll
    for (int off = 32; off >= 1; off >>= 1) part[i] += __shfl_xor(part[i], off);
  }
  const int wvid = t >> 6;
  if ((t & 63) == 0) {
#pragma unroll
    for (int i = 0; i < 16; ++i) ap[wvid][i] = part[i];
  }
  __syncthreads();
  if (t < 32) {
    int i = t & 15, hh = t >> 4;
    float alpha = ap[hh * 2][i] + ap[hh * 2 + 1][i];
    float ee = alpha > 0.f ? alpha : 0.2f * alpha;
    float wv = __expf(fminf(ee, 80.f));  // softmax shift-invariance: no max needed
    wsh[t] = wv;
  }
  __syncthreads();

#pragma unroll
  for (int i = 0; i < 16; ++i) {
    int row = half * 16 + i;
    gsh[row][f] = bf16r(acc[i] * wsh[row]);
  }
  // denom row (f=128) + zero pad rows (f=129..143), this block's 32-col slice
  if (t < 240) {
    int fz = 129 + (t >> 4);
    int j = (t & 15) * 2;
    *(u32*)&gT[(size_t)fz * NN + r0 + j] = 0u;
  }
  if (t < 32) gT[(size_t)128 * NN + r0 + t] = bf16r(wsh[t]);
  __syncthreads();

  const int ff = t >> 1;
  const int jc = (t & 1) * 16;
  u16* dst = gT + (size_t)ff * NN + r0 + jc;
#pragma unroll
  for (int q = 0; q < 4; ++q) {
    ushort4 v;
    v.x = gsh[jc + q * 4 + 0][ff];
    v.y = gsh[jc + q * 4 + 1][ff];
    v.z = gsh[jc + q * 4 + 2][ff];
    v.w = gsh[jc + q * 4 + 3][ff];
    *(ushort4*)(dst + q * 4) = v;
  }
}

// ---- numerP[ks] = adj[:, kchunk] (x) gT[kchunk]  (col 128 = denominator) ----
// Per wave: M=32 (2 row-groups) x N=144. Each B-frag LDS read feeds 2 MFMAs.
// A: register-direct, 4 q-sets, consume-then-refill (one-panel latency).
// B: 144x128 LDS panels, dbuf, global_load_lds w/ pre-swizzled source.
// Sync: one s_barrier per panel with counted vmcnt(16) (9 B older than 16 A).
__global__ __launch_bounds__(256, 2) void k_mm(const int* __restrict__ adj,
                                               const u16* __restrict__ gT,
                                               float* __restrict__ numerP) {
  extern __shared__ char smem[];
  const int t = threadIdx.x;
  const int lane = t & 63;
  const int wv = t >> 6;      // 0..3
  const int i0 = blockIdx.x * 128;
  const int ks = blockIdx.y;
  const int kbase = ks * KCH;
  const int rloc = lane & 15;
  const int ksl = lane >> 4;  // 0..3

  const int* aptr0 = adj + (size_t)(i0 + wv * 32 + rloc) * NN + kbase + ksl * 8;
  const int* aptr1 = aptr0 + (size_t)16 * NN;

  f32x4 acc0[9], acc1[9];
#pragma unroll
  for (int n = 0; n < 9; ++n) {
    acc0[n] = (f32x4){0.f, 0.f, 0.f, 0.f};
    acc1[n] = (f32x4){0.f, 0.f, 0.f, 0.f};
  }

  i32x4 A0a[4], A0b[4], A1a[4], A1b[4];  // statically indexed (full q-unroll)

  auto ISSUE_B = [&](int p, int buf) {
    const char* gTb = (const char*)gT;
#pragma unroll
    for (int i = 0; i < 9; ++i) {
      int gi = wv * 9 + i;  // 0..35; each instr covers f-rows gi*4..gi*4+3
      int fr = gi * 4 + ksl;
      const char* src = gTb + (size_t)fr * (NN * 2) +
                        (size_t)(kbase + p * 128) * 2 +
                        ((rloc * 16) ^ ((fr & 7) << 4));
      char* dst = smem + buf * PANEL_BYTES + gi * 1024;  // HW adds lane*16
      __builtin_amdgcn_global_load_lds((const u32*)src, (u32*)dst, 16, 0, 0);
    }
  };

  auto LDA = [&](int q, int kt) {
    const i32x4* p0 = (const i32x4*)(aptr0 + kt * 32);
    const i32x4* p1 = (const i32x4*)(aptr1 + kt * 32);
    A0a[q] = p0[0];
    A0b[q] = p0[1];
    A1a[q] = p1[0];
    A1b[q] = p1[1];
  };

  auto PACK = [](i32x4 a0, i32x4 a1) {
    u32 p0 = ((u32)a0[0] + ((u32)a0[1] << 16)) * 0x3F80u;
    u32 p1 = ((u32)a0[2] + ((u32)a0[3] << 16)) * 0x3F80u;
    u32 p2 = ((u32)a1[0] + ((u32)a1[1] << 16)) * 0x3F80u;
    u32 p3 = ((u32)a1[2] + ((u32)a1[3] << 16)) * 0x3F80u;
    u32x4 pv = {p0, p1, p2, p3};
    return __builtin_bit_cast(short8, pv);
  };

  // prologue: panel 0 staged; A sets for kt=0..3 in flight
  ISSUE_B(0, 0);
  __builtin_amdgcn_sched_barrier(0);
#pragma unroll
  for (int q = 0; q < 4; ++q) LDA(q, q);
  asm volatile("s_waitcnt vmcnt(16)" ::: "memory");
  __builtin_amdgcn_s_barrier();
  __builtin_amdgcn_sched_barrier(0);

#pragma unroll 1
  for (int p = 0; p < NP; ++p) {
    const int buf = p & 1;
    const bool more = (p + 1 < NP);
    if (more) {
      ISSUE_B(p + 1, buf ^ 1);
      __builtin_amdgcn_sched_barrier(0);
    }
    __builtin_amdgcn_s_setprio(1);
#pragma unroll
    for (int q = 0; q < 4; ++q) {
      // consume set q (loaded one panel ago)...
      short8 fa0 = PACK(A0a[q], A0b[q]);
      short8 fa1 = PACK(A1a[q], A1b[q]);
      // ...then refill set q for the next panel
      if (more) LDA(q, (p + 1) * 4 + q);
      const char* B = smem + buf * PANEL_BYTES;
      const int X = q * 64 + ksl * 16;
#pragma unroll
      for (int n = 0; n < 9; ++n) {
        int fr = n * 16 + rloc;
        short8 fb = *(const short8*)(B + fr * 256 + (X ^ ((fr & 7) << 4)));
        acc0[n] = __builtin_amdgcn_mfma_f32_16x16x32_bf16(fa0, fb, acc0[n], 0, 0, 0);
        acc1[n] = __builtin_amdgcn_mfma_f32_16x16x32_bf16(fa1, fb, acc1[n], 0, 0, 0);
      }
    }
    __builtin_amdgcn_s_setprio(0);
    if (more) {
      asm volatile("s_waitcnt vmcnt(16)" ::: "memory");
      __builtin_amdgcn_s_barrier();
      __builtin_amdgcn_sched_barrier(0);
    }
  }

  float* np0 = numerP + ((size_t)ks * NN + i0 + wv * 32) * FP;
  float* np1 = np0 + (size_t)16 * FP;
#pragma unroll
  for (int qq = 0; qq < 4; ++qq) {
    int row = ksl * 4 + qq;
#pragma unroll
    for (int n = 0; n < 9; ++n) {
      np0[(size_t)row * FP + n * 16 + rloc] = acc0[n][qq];
      np1[(size_t)row * FP + n * 16 + rloc] = acc1[n][qq];
    }
  }
}

// ---- out[row][f] = sum_ks numerP[ks][row][f] / sum_ks numerP[ks][row][128] ----
__global__ __launch_bounds__(256) void k_comb(const float* __restrict__ nP,
                                              float* __restrict__ out) {
  const int idx = blockIdx.x * 256 + threadIdx.x;
  const int row = idx >> 5;
  const int fc = (idx & 31) * 4;
  float4 s = {0.f, 0.f, 0.f, 0.f};
  float d = 0.f;
#pragma unroll
  for (int ks = 0; ks < KSPLIT; ++ks) {
    const float* base = nP + ((size_t)ks * NN + row) * FP;
    float4 nv = *(const float4*)(base + fc);
    s.x += nv.x;
    s.y += nv.y;
    s.z += nv.z;
    s.w += nv.w;
    d += base[128];
  }
  float inv = 1.0f / d;
  float4 o;
  o.x = s.x * inv;
  o.y = s.y * inv;
  o.z = s.z * inv;
  o.w = s.w * inv;
  *(float4*)(out + (size_t)row * FOUT + fc) = o;
}

extern "C" void kernel_launch(void* const* d_in, const int* in_sizes, int n_in,
                              void* d_out, int out_size, void* d_ws, size_t ws_size,
                              hipStream_t stream) {
  const float* x = (const float*)d_in[0];
  const int* adj = (const int*)d_in[1];
  const float* W = (const float*)d_in[2];
  const float* a = (const float*)d_in[3];
  float* out = (float*)d_out;

  char* ws = (char*)d_ws;
  u16* gT = (u16*)(ws + (size_t)1 * 1024 * 1024);           // 2.36 MB (144 x 8192)
  float* numerP = (float*)(ws + (size_t)8 * 1024 * 1024);   // 37.75 MB (8 x 8192 x 144)

  hipLaunchKernelGGL(k_prep, dim3(NN / 32), dim3(256), 0, stream, x, W, a, gT);
  hipLaunchKernelGGL(k_mm, dim3(NN / 128, KSPLIT), dim3(256), 2 * PANEL_BYTES, stream,
                     adj, gT, numerP);
  hipLaunchKernelGGL(k_comb, dim3((NN * 32) / 256), dim3(256), 0, stream, numerP, out);
}

// Round 10
// 108.668 us; speedup vs baseline: 1.2001x; 1.2001x over previous
//
#include <hip/hip_runtime.h>
#include <hip/hip_bf16.h>

#define NN 8192
#define FIN 256
#define FOUT 128
#define KSPLIT 4
#define KCH (NN / KSPLIT)  // 2048
#define NT (KCH / 64)      // 32 tiles

typedef __attribute__((ext_vector_type(8))) short short8;
typedef __attribute__((ext_vector_type(4))) float f32x4;
typedef unsigned short u16;

__device__ inline u16 bf16r(float v) {
  return __builtin_bit_cast(u16, __float2bfloat16(v));
}

// ---- fused: h = x@W (regs), e = leaky_relu(h@a), w = exp(e), gT = bf16(w*h)^T ----
__global__ __launch_bounds__(256) void k_prep(const float* __restrict__ x,
                                              const float* __restrict__ W,
                                              const float* __restrict__ a,
                                              float* __restrict__ wexp,
                                              u16* __restrict__ gT) {
  __shared__ float xs[32 * 256];
  __shared__ float ap[4][16];
  __shared__ float wsh[32];
  __shared__ u16 gsh[32][132];
  const int t = threadIdx.x;
  const int r0 = blockIdx.x * 32;

  const float4* xg = (const float4*)(x + (size_t)r0 * FIN);
  float4* xs4 = (float4*)xs;
#pragma unroll
  for (int p = 0; p < 8; ++p) xs4[p * 256 + t] = xg[p * 256 + t];
  __syncthreads();

  const int f = t & 127;
  const int half = t >> 7;
  float acc[16];
#pragma unroll
  for (int i = 0; i < 16; ++i) acc[i] = 0.f;

  const float4* xsr = (const float4*)(xs + half * 16 * 256);
  for (int k4 = 0; k4 < 64; ++k4) {
    float w0 = W[(k4 * 4 + 0) * FOUT + f];
    float w1 = W[(k4 * 4 + 1) * FOUT + f];
    float w2 = W[(k4 * 4 + 2) * FOUT + f];
    float w3 = W[(k4 * 4 + 3) * FOUT + f];
#pragma unroll
    for (int i = 0; i < 16; ++i) {
      float4 xv = xsr[i * 64 + k4];
      acc[i] = fmaf(xv.x, w0, acc[i]);
      acc[i] = fmaf(xv.y, w1, acc[i]);
      acc[i] = fmaf(xv.z, w2, acc[i]);
      acc[i] = fmaf(xv.w, w3, acc[i]);
    }
  }

  const float af = a[f];
  float part[16];
#pragma unroll
  for (int i = 0; i < 16; ++i) part[i] = acc[i] * af;
#pragma unroll
  for (int i = 0; i < 16; ++i) {
#pragma unroll
    for (int off = 32; off >= 1; off >>= 1) part[i] += __shfl_xor(part[i], off);
  }
  const int wvid = t >> 6;
  if ((t & 63) == 0) {
#pragma unroll
    for (int i = 0; i < 16; ++i) ap[wvid][i] = part[i];
  }
  __syncthreads();
  if (t < 32) {
    int i = t & 15, hh = t >> 4;
    float alpha = ap[hh * 2][i] + ap[hh * 2 + 1][i];
    float ee = alpha > 0.f ? alpha : 0.2f * alpha;
    float wv = __expf(fminf(ee, 80.f));  // softmax shift-invariance: no global max needed
    wsh[t] = wv;
    wexp[r0 + t] = wv;
  }
  __syncthreads();

#pragma unroll
  for (int i = 0; i < 16; ++i) {
    int row = half * 16 + i;
    gsh[row][f] = bf16r(acc[i] * wsh[row]);
  }
  __syncthreads();

  const int ff = t >> 1;
  const int jc = (t & 1) * 16;
  u16* dst = gT + (size_t)ff * NN + r0 + jc;
#pragma unroll
  for (int q = 0; q < 4; ++q) {
    ushort4 v;
    v.x = gsh[jc + q * 4 + 0][ff];
    v.y = gsh[jc + q * 4 + 1][ff];
    v.z = gsh[jc + q * 4 + 2][ff];
    v.w = gsh[jc + q * 4 + 3][ff];
    *(ushort4*)(dst + q * 4) = v;
  }
}

// ---- partial: numer[ks] = adj[:, kchunk] @ g[kchunk], denom[ks] = adj @ w ----
// R2-proven structure: 512 thr (8 waves), dbuf LDS 40KB, reg prefetch 1-deep,
// __syncthreads per tile. Only change vs R2: KSPLIT=4 -> grid 1024 for TLP.
__global__ __launch_bounds__(512, 4) void k_gemm(const int* __restrict__ adj,
                                                 const u16* __restrict__ gT,
                                                 const float* __restrict__ w,
                                                 float* __restrict__ numer,
                                                 float* __restrict__ denom) {
  __shared__ u16 Ash[2][32 * 64];    // [row][k], XOR-swizzled
  __shared__ u16 Bsh[2][128 * 64];   // [f][k],   XOR-swizzled
  __shared__ float denom_sh[32];

  const int t = threadIdx.x;
  const int lane = t & 63;
  const int wvid = t >> 6;
  const int wr = wvid >> 2;
  const int wc = wvid & 3;
  const int r0 = blockIdx.x * 32;
  const int ks = blockIdx.y;
  const size_t kbase = (size_t)ks * KCH;

  const int ar = t >> 4;
  const int ako = (t & 15) * 4;
  const int* adjrow = adj + (size_t)(r0 + ar) * NN + kbase + ako;
  const float* wp = w + kbase + ako;
  const int bfr = t >> 3;
  const int bck = (t & 7) * 8;
  const u16* gTb = gT + kbase + bck;

  f32x4 acc0 = {0.f, 0.f, 0.f, 0.f};
  f32x4 acc1 = {0.f, 0.f, 0.f, 0.f};
  float dpart = 0.f;

  int4 av;
  float4 wq;
  short8 bb0, bb1;

  auto LOAD = [&](int kt) {
    av = *(const int4*)(adjrow + kt * 64);
    wq = *(const float4*)(wp + kt * 64);
    const u16* gp = gTb + (size_t)bfr * NN + kt * 64;
    bb0 = *(const short8*)gp;
    bb1 = *(const short8*)(gp + (size_t)64 * NN);
  };
  auto STORE = [&](int buf) {
    dpart += (av.x ? wq.x : 0.f) + (av.y ? wq.y : 0.f) +
             (av.z ? wq.z : 0.f) + (av.w ? wq.w : 0.f);
    ushort4 a4;
    a4.x = av.x ? (u16)0x3F80 : (u16)0;
    a4.y = av.y ? (u16)0x3F80 : (u16)0;
    a4.z = av.z ? (u16)0x3F80 : (u16)0;
    a4.w = av.w ? (u16)0x3F80 : (u16)0;
    int abyte = ar * 128 + ((ako * 2) ^ ((ar & 7) << 4));
    *(ushort4*)((char*)&Ash[buf][0] + abyte) = a4;
    int bbyte = bfr * 128 + ((bck * 2) ^ ((bfr & 7) << 4));
    *(short8*)((char*)&Bsh[buf][0] + bbyte) = bb0;
    *(short8*)((char*)&Bsh[buf][0] + bbyte + 64 * 128) = bb1;
  };
  auto COMPUTE = [&](int buf) {
    const int swz = (lane & 7) << 4;
    const int arow = wr * 16 + (lane & 15);
    const int bcol = wc * 32 + (lane & 15);
#pragma unroll
    for (int kc = 0; kc < 2; ++kc) {
      int kbyte = kc * 64 + (lane >> 4) * 16;
      short8 afr = *(const short8*)((const char*)&Ash[buf][0] + arow * 128 + (kbyte ^ swz));
      short8 b0  = *(const short8*)((const char*)&Bsh[buf][0] + bcol * 128 + (kbyte ^ swz));
      short8 b1  = *(const short8*)((const char*)&Bsh[buf][0] + (bcol + 16) * 128 + (kbyte ^ swz));
      acc0 = __builtin_amdgcn_mfma_f32_16x16x32_bf16(afr, b0, acc0, 0, 0, 0);
      acc1 = __builtin_amdgcn_mfma_f32_16x16x32_bf16(afr, b1, acc1, 0, 0, 0);
    }
  };

  LOAD(0);
  STORE(0);
  LOAD(1);
  __syncthreads();
  for (int kt = 0; kt < NT; ++kt) {
    int buf = kt & 1;
    if (kt + 1 < NT) STORE(buf ^ 1);
    if (kt + 2 < NT) LOAD(kt + 2);
    COMPUTE(buf);
    __syncthreads();
  }

  dpart += __shfl_xor(dpart, 1);
  dpart += __shfl_xor(dpart, 2);
  dpart += __shfl_xor(dpart, 4);
  dpart += __shfl_xor(dpart, 8);
  if ((t & 15) == 0) denom_sh[ar] = dpart;
  __syncthreads();

#pragma unroll
  for (int q = 0; q < 4; ++q) {
    int row = wr * 16 + (lane >> 4) * 4 + q;
    int col = wc * 32 + (lane & 15);
    float* np = numer + ((size_t)ks * NN + r0 + row) * FOUT + col;
    np[0] = acc0[q];
    np[16] = acc1[q];
  }
  if (t < 32) denom[(size_t)ks * NN + r0 + t] = denom_sh[t];
}

// ---- out = sum_ks(numer) / sum_ks(denom) ----
__global__ __launch_bounds__(256) void k_comb(const float* __restrict__ numer,
                                              const float* __restrict__ denom,
                                              float* __restrict__ out) {
  const int idx = blockIdx.x * 256 + threadIdx.x;
  const int row = idx >> 5;
  const int fc = (idx & 31) * 4;
  float4 s = {0.f, 0.f, 0.f, 0.f};
  float d = 0.f;
#pragma unroll
  for (int ks = 0; ks < KSPLIT; ++ks) {
    float4 nv = *(const float4*)(numer + ((size_t)ks * NN + row) * FOUT + fc);
    s.x += nv.x;
    s.y += nv.y;
    s.z += nv.z;
    s.w += nv.w;
    d += denom[(size_t)ks * NN + row];
  }
  float inv = 1.0f / d;
  float4 o;
  o.x = s.x * inv;
  o.y = s.y * inv;
  o.z = s.z * inv;
  o.w = s.w * inv;
  *(float4*)(out + (size_t)row * FOUT + fc) = o;
}

extern "C" void kernel_launch(void* const* d_in, const int* in_sizes, int n_in,
                              void* d_out, int out_size, void* d_ws, size_t ws_size,
                              hipStream_t stream) {
  const float* x = (const float*)d_in[0];
  const int* adj = (const int*)d_in[1];
  const float* W = (const float*)d_in[2];
  const float* a = (const float*)d_in[3];
  float* out = (float*)d_out;

  char* ws = (char*)d_ws;
  float* wexp = (float*)ws;                                   // 32 KB @ 0
  u16* gT = (u16*)(ws + 64 * 1024);                           // 2 MB @ 64 KB
  float* numer = (float*)(ws + (size_t)4 * 1024 * 1024);      // 16 MB @ 4 MB
  float* denom = (float*)(ws + (size_t)20 * 1024 * 1024);     // 128 KB @ 20 MB

  hipLaunchKernelGGL(k_prep, dim3(NN / 32), dim3(256), 0, stream, x, W, a, wexp, gT);
  hipLaunchKernelGGL(k_gemm, dim3(NN / 32, KSPLIT), dim3(512), 0, stream, adj, gT, wexp,
                     numer, denom);
  hipLaunchKernelGGL(k_comb, dim3((NN * FOUT / 4) / 256), dim3(256), 0, stream, numer,
                     denom, out);
}